// Round 5
// baseline (558.095 us; speedup 1.0000x reference)
//
#include <hip/hip_runtime.h>

#define B_  4
#define N_  2048
#define H_  16
#define HD_ 1024

typedef short  bf16x8 __attribute__((ext_vector_type(8)));
typedef short  bf16x4 __attribute__((ext_vector_type(4)));
typedef float  f32x4  __attribute__((ext_vector_type(4)));

static __device__ __forceinline__ unsigned rne_hi(float f) {
    unsigned u = __builtin_bit_cast(unsigned, f);
    return u + 0x7FFFu + ((u >> 16) & 1u);   // bf16 in bits [31:16]
}
// pack two floats -> (bf16(hi)<<16)|bf16(lo)
static __device__ __forceinline__ unsigned f2bf2pack(float lo, float hi) {
    return __builtin_amdgcn_perm(rne_hi(hi), rne_hi(lo), 0x07060302u);
}
// 8 consecutive fp32 -> bf16x8 fragment
static __device__ __forceinline__ bf16x8 cvt8(const float* p) {
    float4 f0 = *reinterpret_cast<const float4*>(p);
    float4 f1 = *reinterpret_cast<const float4*>(p + 4);
    uint4 u;
    u.x = f2bf2pack(f0.x, f0.y);
    u.y = f2bf2pack(f0.z, f0.w);
    u.z = f2bf2pack(f1.x, f1.y);
    u.w = f2bf2pack(f1.z, f1.w);
    return __builtin_bit_cast(bf16x8, u);
}

// ---------------- projection v3: LDS-free, barrier-free ----------------
// grid (N/256, H, B*3); block 256 = 4 waves, each wave owns 64 tokens.
// q,k out: [b,h,n,64] bf16 (q pre-scaled by 0.125*log2e); v out transposed [b,h,64,n].
// Fragments gathered straight from global (fp32->bf16 in reg); outputs stored
// straight from C-layout as packed b64 global stores. No LDS, no __syncthreads.
__global__ __launch_bounds__(256) void proj_kernel(
    const float* __restrict__ Qv, const float* __restrict__ Kv,
    const float* __restrict__ Vv, const float* __restrict__ WQ,
    const float* __restrict__ WK, const float* __restrict__ WV,
    unsigned short* __restrict__ qs, unsigned short* __restrict__ ks,
    unsigned short* __restrict__ vt)
{
    const int tid  = threadIdx.x;
    const int w    = tid >> 6;
    const int lane = tid & 63;
    const int l15  = lane & 15;
    const int quad = lane >> 4;

    const int i0 = blockIdx.x * 256;
    const int h  = blockIdx.y;
    const int bz = blockIdx.z;
    const int b  = bz / 3;
    const int p  = bz - b * 3;

    const size_t bh = (size_t)b * H_ + h;
    const float* W   = (p == 0) ? WQ : (p == 1) ? WK : WV;
    const float* X   = (p == 0) ? Qv : (p == 1) ? Kv : Vv;
    const int tok0   = i0 + w * 64;

    // W fragments: aw[mt][kh] holds W[16mt+l15][kh*32 + quad*8 + j]
    bf16x8 aw[4][2];
    #pragma unroll
    for (int mt = 0; mt < 4; ++mt)
        #pragma unroll
        for (int kh = 0; kh < 2; ++kh)
            aw[mt][kh] = cvt8(W + (size_t)(16 * mt + l15) * 64 + kh * 32 + quad * 8);

    if (p < 2) {
        const float scl = (p == 0) ? 0.180336880f : 1.f;   // 0.125*log2(e) folded into q
        unsigned short* dst = ((p == 0) ? qs : ks) + (size_t)bh * N_ * 64;
        #pragma unroll
        for (int g = 0; g < 4; ++g) {
            const int tok = tok0 + g * 16 + l15;
            const float* xrow = X + ((size_t)b * N_ + tok) * HD_ + h * 64;
            bf16x8 bx[2] = {cvt8(xrow + quad * 8), cvt8(xrow + 32 + quad * 8)};
            // D[m=dout][n=tok]
            #pragma unroll
            for (int mt = 0; mt < 4; ++mt) {
                f32x4 C = f32x4{0.f, 0.f, 0.f, 0.f};
                #pragma unroll
                for (int kh = 0; kh < 2; ++kh)
                    C = __builtin_amdgcn_mfma_f32_16x16x32_bf16(aw[mt][kh], bx[kh], C, 0, 0, 0);
                // lane holds dout = 16mt+4quad+r, tok = ...+l15  -> b64 store
                uint2 u;
                u.x = f2bf2pack(C[0] * scl, C[1] * scl);
                u.y = f2bf2pack(C[2] * scl, C[3] * scl);
                *reinterpret_cast<uint2*>(dst + (size_t)tok * 64 + 16 * mt + 4 * quad) = u;
            }
        }
    } else {
        unsigned short* vdst = vt + (size_t)bh * 64 * N_;
        #pragma unroll
        for (int g = 0; g < 4; ++g) {
            const int tokr = tok0 + g * 16 + l15;
            const float* xrow = X + ((size_t)b * N_ + tokr) * HD_ + h * 64;
            bf16x8 ax[2] = {cvt8(xrow + quad * 8), cvt8(xrow + 32 + quad * 8)};
            // D[m=tok][n=dout]
            #pragma unroll
            for (int nt = 0; nt < 4; ++nt) {
                f32x4 C = f32x4{0.f, 0.f, 0.f, 0.f};
                #pragma unroll
                for (int kh = 0; kh < 2; ++kh)
                    C = __builtin_amdgcn_mfma_f32_16x16x32_bf16(ax[kh], aw[nt][kh], C, 0, 0, 0);
                // lane holds tok = tok0+g*16+4quad+r, dout = 16nt+l15 -> b64 store into vt[dout][tok]
                uint2 u;
                u.x = f2bf2pack(C[0], C[1]);
                u.y = f2bf2pack(C[2], C[3]);
                *reinterpret_cast<uint2*>(vdst + (size_t)(16 * nt + l15) * N_ + tok0 + g * 16 + 4 * quad) = u;
            }
        }
    }
}

// ---------------- transposed flash attention (rt=2: 32 q-rows/wave) ----------------
// S^T = K Q^T, O^T = V^T P^T. P never touches LDS: S^T C-layout registers ARE
// the P B-fragment under k-permutation sigma(k): j = {k5,k2,k4,k3,k1:0}.
// grid: (N/128, B*H), block 256 = 4 waves.
__global__ __launch_bounds__(256, 4) void attn_kernel(
    const unsigned short* __restrict__ qs, const unsigned short* __restrict__ ks,
    const unsigned short* __restrict__ vt, const int* __restrict__ maskp,
    float* __restrict__ out)
{
    __shared__ __align__(16) unsigned short Ks[64][72];   // stride 36 dw: b128 reads uniform
    __shared__ __align__(16) unsigned short Vt[64][68];   // stride 34 dw: b64 reads conflict-free
    __shared__ float kb[64];

    const int tid  = threadIdx.x;
    const int w    = tid >> 6;
    const int lane = tid & 63;
    const int l15  = lane & 15;
    const int quad = lane >> 4;

    const int i0 = blockIdx.x * 128;
    const int bh = blockIdx.y;
    const int b  = bh >> 4;
    const int h  = bh & 15;
    const int qrow0 = i0 + w * 32;

    // Q fragments (B-operand) for 2 row-tiles, straight from global
    bf16x8 aq[2][2];
    float  qm[2];
    #pragma unroll
    for (int rt = 0; rt < 2; ++rt) {
        const unsigned short* qrow = qs + ((size_t)bh * N_ + qrow0 + rt * 16 + l15) * 64;
        aq[rt][0] = *reinterpret_cast<const bf16x8*>(qrow + quad * 8);
        aq[rt][1] = *reinterpret_cast<const bf16x8*>(qrow + 32 + quad * 8);
        qm[rt] = maskp[b * N_ + qrow0 + rt * 16 + l15] ? 1.f : 0.f;
    }

    bf16x8 aones;
    #pragma unroll
    for (int j = 0; j < 8; ++j) aones[j] = (short)0x3F80;

    f32x4 O[2][4];     // [rt][ct] : O^T[d-block ct][qrow-block rt]
    f32x4 L[2];
    #pragma unroll
    for (int rt = 0; rt < 2; ++rt) {
        L[rt] = f32x4{0.f, 0.f, 0.f, 0.f};
        #pragma unroll
        for (int c = 0; c < 4; ++c) O[rt][c] = f32x4{0.f, 0.f, 0.f, 0.f};
    }

    const unsigned short* kbase = ks + (size_t)bh * N_ * 64;
    const unsigned short* vbase = vt + (size_t)bh * 64 * N_;

    for (int kv0 = 0; kv0 < N_; kv0 += 64) {
        __syncthreads();
        // stage K rows [64][64] (b128, bank-uniform) and V^T rows (b64 pairs)
        #pragma unroll
        for (int it = 0; it < 2; ++it) {
            int idx = tid + it * 256;          // 0..511
            int r = idx >> 3, g = idx & 7;
            *reinterpret_cast<uint4*>(&Ks[r][g * 8]) =
                *reinterpret_cast<const uint4*>(kbase + (size_t)(kv0 + r) * 64 + g * 8);
        }
        #pragma unroll
        for (int it = 0; it < 4; ++it) {
            int idx = tid + it * 256;          // 0..1023, 8B chunks
            int r = idx >> 4, g2 = idx & 15;
            *reinterpret_cast<uint2*>(&Vt[r][g2 * 4]) =
                *reinterpret_cast<const uint2*>(vbase + (size_t)r * N_ + kv0 + g2 * 4);
        }
        if (tid < 64) kb[tid] = maskp[b * N_ + kv0 + tid] ? 0.f : -1e30f;
        __syncthreads();

        // K A-fragments (shared across both rt) and V A-fragments
        bf16x8 ak[4][2];
        #pragma unroll
        for (int ct = 0; ct < 4; ++ct)
            #pragma unroll
            for (int kh = 0; kh < 2; ++kh)
                ak[ct][kh] = *reinterpret_cast<const bf16x8*>(&Ks[ct * 16 + l15][kh * 32 + quad * 8]);

        bf16x8 av[4][2];
        #pragma unroll
        for (int ct = 0; ct < 4; ++ct)
            #pragma unroll
            for (int kh = 0; kh < 2; ++kh) {
                bf16x4 lo = *reinterpret_cast<const bf16x4*>(&Vt[ct * 16 + l15][kh * 32 + quad * 4]);
                bf16x4 hi = *reinterpret_cast<const bf16x4*>(&Vt[ct * 16 + l15][kh * 32 + 16 + quad * 4]);
                av[ct][kh] = bf16x8{lo[0], lo[1], lo[2], lo[3], hi[0], hi[1], hi[2], hi[3]};
            }

        f32x4 kbv[4];
        #pragma unroll
        for (int ct = 0; ct < 4; ++ct)
            kbv[ct] = *reinterpret_cast<const f32x4*>(&kb[ct * 16 + quad * 4]);

        #pragma unroll
        for (int rt = 0; rt < 2; ++rt) {
            // S^T: lane holds S[qrow=rt*16+l15][j=16ct+4q+r]
            f32x4 S[4];
            #pragma unroll
            for (int ct = 0; ct < 4; ++ct) {
                S[ct] = f32x4{0.f, 0.f, 0.f, 0.f};
                #pragma unroll
                for (int kh = 0; kh < 2; ++kh)
                    S[ct] = __builtin_amdgcn_mfma_f32_16x16x32_bf16(ak[ct][kh], aq[rt][kh], S[ct], 0, 0, 0);
            }
            // masked exp2 (q pre-scaled by log2e); pack directly into P B-fragments
            unsigned pk[4][2];
            #pragma unroll
            for (int ct = 0; ct < 4; ++ct) {
                float e0 = __builtin_amdgcn_exp2f((S[ct][0] + kbv[ct][0]) * qm[rt]);
                float e1 = __builtin_amdgcn_exp2f((S[ct][1] + kbv[ct][1]) * qm[rt]);
                float e2 = __builtin_amdgcn_exp2f((S[ct][2] + kbv[ct][2]) * qm[rt]);
                float e3 = __builtin_amdgcn_exp2f((S[ct][3] + kbv[ct][3]) * qm[rt]);
                pk[ct][0] = f2bf2pack(e0, e1);
                pk[ct][1] = f2bf2pack(e2, e3);
            }
            bf16x8 ap[2];
            #pragma unroll
            for (int kh = 0; kh < 2; ++kh) {
                uint4 u = uint4{pk[2 * kh][0], pk[2 * kh][1], pk[2 * kh + 1][0], pk[2 * kh + 1][1]};
                ap[kh] = __builtin_bit_cast(bf16x8, u);
            }
            // row-sums: every lane gets its own qrow's L
            #pragma unroll
            for (int kh = 0; kh < 2; ++kh)
                L[rt] = __builtin_amdgcn_mfma_f32_16x16x32_bf16(aones, ap[kh], L[rt], 0, 0, 0);
            // O^T += V^T P^T
            #pragma unroll
            for (int ct = 0; ct < 4; ++ct)
                #pragma unroll
                for (int kh = 0; kh < 2; ++kh)
                    O[rt][ct] = __builtin_amdgcn_mfma_f32_16x16x32_bf16(av[ct][kh], ap[kh], O[rt][ct], 0, 0, 0);
        }
    }

    // epilogue: lane (q,l15) holds O^T[d=16ct+4q+r][qrow=rt*16+l15]; L[rt] comps all equal
    #pragma unroll
    for (int rt = 0; rt < 2; ++rt) {
        float inv = 1.f / L[rt][0];
        float* orow = out + ((size_t)b * N_ + qrow0 + rt * 16 + l15) * HD_ + h * 64 + quad * 4;
        #pragma unroll
        for (int ct = 0; ct < 4; ++ct)
            #pragma unroll
            for (int r = 0; r < 4; ++r)
                orow[ct * 16 + r] = O[rt][ct][r] * inv;
    }
}

extern "C" void kernel_launch(void* const* d_in, const int* in_sizes, int n_in,
                              void* d_out, int out_size, void* d_ws, size_t ws_size,
                              hipStream_t stream)
{
    const float* Qv  = (const float*)d_in[0];
    const float* Kv  = (const float*)d_in[1];
    const float* Vv  = (const float*)d_in[2];
    const float* WQ  = (const float*)d_in[3];
    const float* WK  = (const float*)d_in[4];
    const float* WV  = (const float*)d_in[5];
    const int*   msk = (const int*)d_in[6];
    float* out = (float*)d_out;

    const size_t per = (size_t)B_ * H_ * N_ * 64;   // 8.4M elems, bf16
    unsigned short* qsb = (unsigned short*)d_ws;
    unsigned short* ksb = qsb + per;
    unsigned short* vtb = ksb + per;

    proj_kernel<<<dim3(N_ / 256, H_, B_ * 3), 256, 0, stream>>>(Qv, Kv, Vv, WQ, WK, WV, qsb, ksb, vtb);
    attn_kernel<<<dim3(N_ / 128, B_ * H_), 256, 0, stream>>>(qsb, ksb, vtb, msk, out);
}